// Round 11
// baseline (267.335 us; speedup 1.0000x reference)
//
#include <hip/hip_runtime.h>
#include <hip/hip_bf16.h>

#define BGR   128
#define NPER  1024
#define NK    7
#define NNODES (BGR*NPER)

typedef __attribute__((ext_vector_type(8))) short short8;
typedef __attribute__((ext_vector_type(8))) unsigned short ushort8;
typedef __attribute__((ext_vector_type(4))) float floatx4;

static __device__ __forceinline__ float bf2f(unsigned short u) {
    unsigned int x = ((unsigned int)u) << 16;
    return __builtin_bit_cast(float, x);
}
static __device__ __forceinline__ unsigned short f2bf(float f) {
    unsigned int x = __builtin_bit_cast(unsigned int, f);
    unsigned int lsb = (x >> 16) & 1u;
    x += 0x7fffu + lsb;
    return (unsigned short)(x >> 16);
}

// ---------------- 0: prep — float4 {x,y,z,|q|^2} for scalar-pipe candidate streaming ---------
__global__ __launch_bounds__(256) void prep_pos_kernel(const float* __restrict__ pos,
                                                       floatx4* __restrict__ p4) {
    int i = blockIdx.x * 256 + threadIdx.x;
    if (i < NNODES) {
        float x = pos[(size_t)i*3], y = pos[(size_t)i*3+1], z = pos[(size_t)i*3+2];
        floatx4 v;
        v.x = x; v.y = y; v.z = z;
        v.w = fmaf(x, x, fmaf(y, y, z * z));
        p4[i] = v;
    }
}

// ---------------- 1: kNN — split-scan, candidates via s_load (scalar pipe), med3 chain -------
// Candidate index is wave-uniform (readfirstlane'd half + loop var) -> cp[j] compiles to
// s_load into SGPRs: zero LDS/VMEM traffic in the scan; VALU ops take SGPR operands.
// d' = |q|^2 - 2 p.q (order == |p-q|^2). Self d' = -|p|^2 = global min -> sits in slot 0 of
// its half. Merge: 7 smallest of union(A[1..7], B[0..7]) = min(A[i+1], B[6-i]).
__global__ __launch_bounds__(256) void knn_kernel(const floatx4* __restrict__ p4,
                                                  int* __restrict__ idx) {
    __shared__ float ex[256][9];            // merge exchange (padded rows)
    int g     = blockIdx.x >> 3;
    int qbase = (blockIdx.x & 7) << 7;      // 128 queries per block
    int base  = g * NPER;
    int qi = qbase + (threadIdx.x & 127);   // query this thread serves
    int hf = __builtin_amdgcn_readfirstlane((int)(threadIdx.x >> 7)); // candidate half (SGPR)
    floatx4 me = p4[base + qi];
    float m2x = -2.f * me.x, m2y = -2.f * me.y, m2z = -2.f * me.z;
    const floatx4* cp = p4 + base;

    float b0=3e38f,b1=3e38f,b2=3e38f,b3=3e38f,b4=3e38f,b5=3e38f,b6=3e38f,b7=3e38f;
    int j0base = hf << 9;
    for (int j0 = j0base; j0 < j0base + 512; j0 += 8) {
        floatx4 qq[8];
        #pragma unroll
        for (int u = 0; u < 8; ++u) qq[u] = cp[j0 + u];   // uniform addr -> s_load_dwordx4
        #pragma unroll
        for (int u = 0; u < 8; ++u) {
            floatx4 q = qq[u];
            float d = fmaf(m2x, q.x, fmaf(m2y, q.y, fmaf(m2z, q.z, q.w)));
            unsigned int ub = (__builtin_bit_cast(unsigned int, d) & 0xFFFFFC00u)
                              | (unsigned int)(j0 + u);
            float t = __builtin_bit_cast(float, ub);
            float n7 = __builtin_amdgcn_fmed3f(b6, b7, t);
            float n6 = __builtin_amdgcn_fmed3f(b5, b6, t);
            float n5 = __builtin_amdgcn_fmed3f(b4, b5, t);
            float n4 = __builtin_amdgcn_fmed3f(b3, b4, t);
            float n3 = __builtin_amdgcn_fmed3f(b2, b3, t);
            float n2 = __builtin_amdgcn_fmed3f(b1, b2, t);
            float n1 = __builtin_amdgcn_fmed3f(b0, b1, t);
            b0 = fminf(b0, t);
            b1 = n1; b2 = n2; b3 = n3; b4 = n4; b5 = n5; b6 = n6; b7 = n7;
        }
    }
    float* er = ex[threadIdx.x];
    er[0]=b0; er[1]=b1; er[2]=b2; er[3]=b3; er[4]=b4; er[5]=b5; er[6]=b6; er[7]=b7;
    __syncthreads();
    if (threadIdx.x < 128) {
        int sh = qi >> 9;                   // which half contains self
        const float* A  = ex[threadIdx.x + (sh << 7)];        // self-half list (A[0]=self)
        const float* Bo = ex[threadIdx.x + ((1 - sh) << 7)];  // other-half list
        int* op = idx + (size_t)(base + qi) * NK;
        #pragma unroll
        for (int i = 0; i < 7; ++i) {
            float mm = fminf(A[i + 1], Bo[6 - i]);
            op[i] = base + (int)(__builtin_bit_cast(unsigned int, mm) & 1023u);
        }
    }
}

// ---------------- 2: feat1 — x(16) -> packed qv1/ks1 uint[n][64] (lo=q/k, hi=v/s) ----------------
__global__ __launch_bounds__(256) void feat1_kernel(
    const float* __restrict__ x,
    const float* __restrict__ wk, const float* __restrict__ bk,
    const float* __restrict__ wq, const float* __restrict__ bq,
    const float* __restrict__ wv, const float* __restrict__ bv,
    const float* __restrict__ wsm, const float* __restrict__ bs,
    unsigned int* __restrict__ qv, unsigned int* __restrict__ ks) {
    int c = threadIdx.x & 63;
    float Wk[16], Wq[16], Wv[16], Ws[16];
    #pragma unroll
    for (int k = 0; k < 16; ++k) {
        Wk[k] = wk[k*64+c]; Wq[k] = wq[k*64+c]; Wv[k] = wv[k*64+c]; Ws[k] = wsm[k*64+c];
    }
    float Bk = bk[c], Bq = bq[c], Bv = bv[c], Bs = bs[c];
    int wave = blockIdx.x * (blockDim.x >> 6) + (threadIdx.x >> 6);
    int nw   = gridDim.x * (blockDim.x >> 6);
    for (int n = wave; n < NNODES; n += nw) {
        const float* xr = x + (size_t)n * 16;
        float ak = Bk, aq = Bq, av = Bv, as = Bs;
        #pragma unroll
        for (int k = 0; k < 16; ++k) {
            float xv = xr[k];
            ak += xv * Wk[k]; aq += xv * Wq[k]; av += xv * Wv[k]; as += xv * Ws[k];
        }
        size_t o = (size_t)n * 64 + c;
        qv[o] = ((unsigned int)f2bf(av) << 16) | f2bf(aq);
        ks[o] = ((unsigned int)f2bf(as) << 16) | f2bf(ak);
    }
}

// ---------------- 3: gated conv — scalar addressing + rcp sigmoid ----------------
template<int C>
__global__ __launch_bounds__(256) void conv_kernel(
    const unsigned int* __restrict__ qv, const unsigned int* __restrict__ ks,
    const int* __restrict__ idx, unsigned short* __restrict__ h,
    float* __restrict__ part) {
    const int NPB = 256 / C;
    int c   = threadIdx.x & (C - 1);
    int sub = __builtin_amdgcn_readfirstlane((int)(threadIdx.x / C));
    int b     = blockIdx.x;            // 4096 total = 128 graphs x 32
    int xcd   = b & 7;
    int chunk = b >> 3;
    int graph = xcd * 16 + (chunk >> 5);
    int nblk  = chunk & 31;
    int n0 = graph * NPER + nblk * 32;
    float s = 0.f, s2 = 0.f;
    #pragma unroll 2
    for (int i = sub; i < 32; i += NPB) {
        int n = n0 + i;                // wave-uniform (sub is SGPR)
        const int* nb = idx + (size_t)n * NK;
        unsigned int ku = ks[(size_t)n * C + c];
        float kv  = bf2f((unsigned short)(ku & 0xFFFF));
        float acc = bf2f((unsigned short)(ku >> 16));
        #pragma unroll
        for (int k = 0; k < NK; ++k) {
            int j = __builtin_amdgcn_readfirstlane(nb[k]);   // SGPR neighbor index
            const unsigned int* p = qv + (size_t)j * C;      // SGPR base
            unsigned int u = p[c];                           // s[base] + v_off load
            float qvv = bf2f((unsigned short)(u & 0xFFFF));
            float vvv = bf2f((unsigned short)(u >> 16));
            float t = kv + qvv;
            float sg = __builtin_amdgcn_rcpf(1.f + __expf(-t));
            acc = fmaf(sg, vvv, acc);
        }
        unsigned short hb = f2bf(acc);
        h[(size_t)n * C + c] = hb;
        float hv = bf2f(hb);
        s += hv; s2 += hv * hv;
    }
    __shared__ float ls[256], ls2[256];
    ls[threadIdx.x] = s; ls2[threadIdx.x] = s2;
    __syncthreads();
    if (threadIdx.x < C) {
        #pragma unroll
        for (int l = 1; l < NPB; ++l) { s += ls[threadIdx.x + l*C]; s2 += ls2[threadIdx.x + l*C]; }
        part[(size_t)blockIdx.x * 2 * C + threadIdx.x]     = s;
        part[(size_t)blockIdx.x * 2 * C + C + threadIdx.x] = s2;
    }
}

// ---------------- 4: BN finalize over 4096 block-partials (one block per channel) ----------------
template<int C>
static __device__ __forceinline__ void bnfin_body(
    const float* __restrict__ part, const float* __restrict__ gamma,
    const float* __restrict__ beta, float* __restrict__ ss,
    int c, float* ls, float* ls2) {
    float s = 0.f, s2 = 0.f;
    for (int b = threadIdx.x; b < 4096; b += 256) {
        s  += part[(size_t)b * 2 * C + c];
        s2 += part[(size_t)b * 2 * C + C + c];
    }
    ls[threadIdx.x] = s; ls2[threadIdx.x] = s2;
    __syncthreads();
    for (int st = 128; st > 0; st >>= 1) {
        if (threadIdx.x < st) { ls[threadIdx.x] += ls[threadIdx.x+st]; ls2[threadIdx.x] += ls2[threadIdx.x+st]; }
        __syncthreads();
    }
    if (threadIdx.x == 0) {
        float m   = ls[0] / (float)NNODES;
        float var = ls2[0] / (float)NNODES - m * m;
        float inv = rsqrtf(var + 1e-5f);
        float sc  = gamma[c] * inv;
        ss[c]     = sc;
        ss[C + c] = beta[c] - m * sc;
    }
}

template<int C>
__global__ __launch_bounds__(256) void bnfin_kernel(
    const float* __restrict__ part, const float* __restrict__ gamma,
    const float* __restrict__ beta, float* __restrict__ ss) {
    __shared__ float ls[256], ls2[256];
    bnfin_body<C>(part, gamma, beta, ss, blockIdx.x, ls, ls2);
}

// ---------------- 5: merged BN1-finalize (blocks 0..63) + wfrag (blocks 64..127) ----------------
__global__ __launch_bounds__(256) void fin1_wfrag_kernel(
    const float* __restrict__ part, const float* __restrict__ gamma,
    const float* __restrict__ beta, float* __restrict__ ss,
    const float* __restrict__ w0, const float* __restrict__ w1,
    const float* __restrict__ w2, const float* __restrict__ w3,
    unsigned short* __restrict__ frag) {
    __shared__ float ls[256], ls2[256];
    if (blockIdx.x < 64) {
        bnfin_body<64>(part, gamma, beta, ss, blockIdx.x, ls, ls2);
        return;
    }
    int s  = blockIdx.x - 64;
    if (threadIdx.x >= 64) return;
    int m  = s >> 4;
    int kt = (s >> 3) & 1;
    int ct = s & 7;
    const float* w = (m == 0) ? w0 : (m == 1) ? w1 : (m == 2) ? w2 : w3;
    int l = threadIdx.x;
    int col = ct * 16 + (l & 15);
    int kbase = kt * 32 + (l >> 4) * 8;
    unsigned short* out = frag + ((size_t)s * 64 + l) * 8;
    #pragma unroll
    for (int e = 0; e < 8; ++e) out[e] = f2bf(w[(size_t)(kbase + e) * 128 + col]);
}

// ---------------- 7: feat2 — BN1+ReLU fused load, MFMA, LDS-exchange dword stores -------------
__global__ __launch_bounds__(256) void feat2_kernel(
    const unsigned short* __restrict__ h1n, const unsigned short* __restrict__ frag,
    const float* __restrict__ ss1,
    const float* __restrict__ b0, const float* __restrict__ b1,
    const float* __restrict__ b2, const float* __restrict__ b3,
    unsigned int* __restrict__ qv2, unsigned int* __restrict__ ks2) {
    __shared__ unsigned short xh[2][2][16][17];   // [ct parity][v/s][row][col+pad]
    int nt = blockIdx.x;
    int m  = threadIdx.x >> 6;
    int l  = threadIdx.x & 63;
    const float* bm = (m == 0) ? b0 : (m == 1) ? b1 : (m == 2) ? b2 : b3;
    int lr = l & 15;
    int gq = l >> 4;
    int n  = nt * 16 + lr;
    const unsigned short* ar = h1n + (size_t)n * 64 + gq * 8;
    short8 a0r = *(const short8*)ar;
    short8 a1r = *(const short8*)(ar + 32);
    short8 a0, a1;
    #pragma unroll
    for (int e = 0; e < 8; ++e) {
        int c0 = gq * 8 + e;
        float f0 = bf2f((unsigned short)a0r[e]) * ss1[c0] + ss1[64 + c0];
        a0[e] = (short)f2bf(fmaxf(f0, 0.f));
        int c1 = 32 + gq * 8 + e;
        float f1 = bf2f((unsigned short)a1r[e]) * ss1[c1] + ss1[64 + c1];
        a1[e] = (short)f2bf(fmaxf(f1, 0.f));
    }
    #pragma unroll
    for (int ct = 0; ct < 8; ++ct) {
        size_t fb0 = ((size_t)(m * 16 + ct)     * 64 + l) * 8;
        size_t fb1 = ((size_t)(m * 16 + 8 + ct) * 64 + l) * 8;
        short8 w0 = *(const short8*)(frag + fb0);
        short8 w1 = *(const short8*)(frag + fb1);
        float bv = bm[ct * 16 + lr];
        floatx4 acc = {bv, bv, bv, bv};
        acc = __builtin_amdgcn_mfma_f32_16x16x32_bf16(a0, w0, acc, 0, 0, 0);
        acc = __builtin_amdgcn_mfma_f32_16x16x32_bf16(a1, w1, acc, 0, 0, 0);
        if (m >= 2) {
            #pragma unroll
            for (int r = 0; r < 4; ++r)
                xh[ct & 1][m - 2][gq * 4 + r][lr] = f2bf(acc[r]);
        }
        __syncthreads();
        if (m < 2) {
            unsigned int* od = (m == 1) ? qv2 : ks2;
            int set = (m == 1) ? 0 : 1;
            #pragma unroll
            for (int r = 0; r < 4; ++r) {
                unsigned int lo = f2bf(acc[r]);
                unsigned int hi = xh[ct & 1][set][gq * 4 + r][lr];
                od[(size_t)(nt * 16 + gq * 4 + r) * 128 + ct * 16 + lr] = (hi << 16) | lo;
            }
        }
    }
}

// ---------------- 8: mean-pool with fused BN2+ReLU, two-stage ----------------
__global__ __launch_bounds__(256) void pool_partial_kernel(const unsigned short* __restrict__ h2,
                                                           const float* __restrict__ ss2,
                                                           float* __restrict__ part) {
    int g = blockIdx.x >> 2;
    int q = blockIdx.x & 3;
    int c = threadIdx.x & 127;
    int isub = threadIdx.x >> 7;  // 0..1
    float sc = ss2[c], sh = ss2[128 + c];
    float acc = 0.f;
    const unsigned short* hp = h2 + ((size_t)g * NPER + q * 256) * 128;
    for (int i = isub; i < 256; i += 2)
        acc += fmaxf(bf2f(hp[(size_t)i * 128 + c]) * sc + sh, 0.f);
    __shared__ float red[256];
    red[threadIdx.x] = acc;
    __syncthreads();
    if (threadIdx.x < 128)
        part[(size_t)blockIdx.x * 128 + c] = acc + red[threadIdx.x + 128];
}

__global__ void pool_final_kernel(const float* __restrict__ part, float* __restrict__ out) {
    int g = blockIdx.x, c = threadIdx.x;
    float s = part[(size_t)(g*4+0)*128+c] + part[(size_t)(g*4+1)*128+c]
            + part[(size_t)(g*4+2)*128+c] + part[(size_t)(g*4+3)*128+c];
    out[(size_t)g * 128 + c] = s * (1.f / 1024.f);
}

extern "C" void kernel_launch(void* const* d_in, const int* in_sizes, int n_in,
                              void* d_out, int out_size, void* d_ws, size_t ws_size,
                              hipStream_t stream) {
    const float* x   = (const float*)d_in[0];
    const float* pos = (const float*)d_in[1];
    const float* wk1 = (const float*)d_in[3];
    const float* bk1 = (const float*)d_in[4];
    const float* wq1 = (const float*)d_in[5];
    const float* bq1 = (const float*)d_in[6];
    const float* wv1 = (const float*)d_in[7];
    const float* bv1 = (const float*)d_in[8];
    const float* ws1 = (const float*)d_in[9];
    const float* bs1 = (const float*)d_in[10];
    const float* g1  = (const float*)d_in[11];
    const float* be1 = (const float*)d_in[12];
    const float* wk2 = (const float*)d_in[13];
    const float* bk2 = (const float*)d_in[14];
    const float* wq2 = (const float*)d_in[15];
    const float* bq2 = (const float*)d_in[16];
    const float* wv2 = (const float*)d_in[17];
    const float* bv2 = (const float*)d_in[18];
    const float* ws2 = (const float*)d_in[19];
    const float* bs2 = (const float*)d_in[20];
    const float* g2  = (const float*)d_in[21];
    const float* be2 = (const float*)d_in[22];
    float* out = (float*)d_out;

    const size_t SZ_QV1 = (size_t)NNODES * 64 * 4;   // 32 MiB (uint[n][64])
    const size_t SZ_QV2 = (size_t)NNODES * 128 * 4;  // 64 MiB (uint[n][128])

    char* ws = (char*)d_ws;
    size_t off = 0;
    auto alloc = [&](size_t b) { size_t o = off; off += (b + 255) & ~(size_t)255; return o; };

    int* idx              = (int*)(ws + alloc((size_t)NNODES * NK * 4));
    size_t o_region       = alloc(2 * SZ_QV2);      // layer-2 qv/ks; layer-1 aliased in front
    unsigned int* qv1     = (unsigned int*)(ws + o_region);
    unsigned int* ks1     = (unsigned int*)(ws + o_region + SZ_QV1);
    unsigned int* qv2     = (unsigned int*)(ws + o_region);
    unsigned int* ks2     = (unsigned int*)(ws + o_region + SZ_QV2);
    unsigned short* h1    = (unsigned short*)(ws + alloc((size_t)NNODES * 64 * 2));
    unsigned short* h2    = (unsigned short*)(ws + alloc((size_t)NNODES * 128 * 2));
    unsigned short* frag  = (unsigned short*)(ws + alloc(64 * 64 * 8 * 2));
    float* part           = (float*)(ws + alloc((size_t)4096 * 2 * 128 * 4));
    float* ss1            = (float*)(ws + alloc(2 * 64 * 4));
    float* ss2            = (float*)(ws + alloc(2 * 128 * 4));
    floatx4* p4           = (floatx4*)(ws + alloc((size_t)NNODES * 16));
    (void)ws_size; (void)in_sizes; (void)n_in; (void)out_size;

    prep_pos_kernel<<<NNODES / 256, 256, 0, stream>>>(pos, p4);
    knn_kernel<<<BGR * 8, 256, 0, stream>>>(p4, idx);
    feat1_kernel<<<1024, 256, 0, stream>>>(x, wk1, bk1, wq1, bq1, wv1, bv1, ws1, bs1,
                                           qv1, ks1);
    conv_kernel<64><<<NNODES / 32, 256, 0, stream>>>(qv1, ks1, idx, h1, part);
    fin1_wfrag_kernel<<<128, 256, 0, stream>>>(part, g1, be1, ss1,
                                               wk2, wq2, wv2, ws2, frag);
    feat2_kernel<<<NNODES / 16, 256, 0, stream>>>(h1, frag, ss1, bk2, bq2, bv2, bs2,
                                                  qv2, ks2);
    conv_kernel<128><<<NNODES / 32, 256, 0, stream>>>(qv2, ks2, idx, h2, part);
    bnfin_kernel<128><<<128, 256, 0, stream>>>(part, g2, be2, ss2);
    pool_partial_kernel<<<BGR * 4, 256, 0, stream>>>(h2, ss2, part);
    pool_final_kernel<<<BGR, 128, 0, stream>>>(part, out);
}

// Round 12
// 241.496 us; speedup vs baseline: 1.1070x; 1.1070x over previous
//
#include <hip/hip_runtime.h>
#include <hip/hip_bf16.h>

#define BGR   128
#define NPER  1024
#define NK    7
#define NNODES (BGR*NPER)

typedef __attribute__((ext_vector_type(8))) short short8;
typedef __attribute__((ext_vector_type(8))) unsigned short ushort8;
typedef __attribute__((ext_vector_type(4))) float floatx4;

static __device__ __forceinline__ float bf2f(unsigned short u) {
    unsigned int x = ((unsigned int)u) << 16;
    return __builtin_bit_cast(float, x);
}
static __device__ __forceinline__ unsigned short f2bf(float f) {
    unsigned int x = __builtin_bit_cast(unsigned int, f);
    unsigned int lsb = (x >> 16) & 1u;
    x += 0x7fffu + lsb;
    return (unsigned short)(x >> 16);
}

// ---------------- 1: kNN — split-scan (2 threads/query), LDS candidates, med3 chain ---------
// (round-10 version; idx rows padded to stride 8 for aligned dwordx8 scalar reads in conv)
__global__ __launch_bounds__(256) void knn_kernel(const float* __restrict__ pos,
                                                  int* __restrict__ idx) {
    __shared__ __align__(16) floatx4 sp[NPER];
    __shared__ float ex[256][9];
    int g     = blockIdx.x >> 3;
    int qbase = (blockIdx.x & 7) << 7;
    int base  = g * NPER;
    const float* pg = pos + (size_t)base * 3;
    for (int t = threadIdx.x; t < NPER * 3; t += 256) {
        float v = pg[t];
        int j = t / 3, comp = t - j * 3;
        ((float*)&sp[j])[comp] = v;
    }
    __syncthreads();
    for (int j = threadIdx.x; j < NPER; j += 256) {
        floatx4 q = sp[j];
        sp[j].w = fmaf(q.x, q.x, fmaf(q.y, q.y, q.z * q.z));
    }
    __syncthreads();

    int qi = qbase + (threadIdx.x & 127);
    int hf = threadIdx.x >> 7;
    floatx4 me = sp[qi];
    float m2x = -2.f * me.x, m2y = -2.f * me.y, m2z = -2.f * me.z;

    float b0=3e38f,b1=3e38f,b2=3e38f,b3=3e38f,b4=3e38f,b5=3e38f,b6=3e38f,b7=3e38f;
    int j0base = hf << 9;
    for (int j0 = j0base; j0 < j0base + 512; j0 += 8) {
        #pragma unroll
        for (int u = 0; u < 8; ++u) {
            floatx4 q = sp[j0 + u];
            float d = fmaf(m2x, q.x, fmaf(m2y, q.y, fmaf(m2z, q.z, q.w)));
            unsigned int ub = (__builtin_bit_cast(unsigned int, d) & 0xFFFFFC00u)
                              | (unsigned int)(j0 + u);
            float t = __builtin_bit_cast(float, ub);
            float n7 = __builtin_amdgcn_fmed3f(b6, b7, t);
            float n6 = __builtin_amdgcn_fmed3f(b5, b6, t);
            float n5 = __builtin_amdgcn_fmed3f(b4, b5, t);
            float n4 = __builtin_amdgcn_fmed3f(b3, b4, t);
            float n3 = __builtin_amdgcn_fmed3f(b2, b3, t);
            float n2 = __builtin_amdgcn_fmed3f(b1, b2, t);
            float n1 = __builtin_amdgcn_fmed3f(b0, b1, t);
            b0 = fminf(b0, t);
            b1 = n1; b2 = n2; b3 = n3; b4 = n4; b5 = n5; b6 = n6; b7 = n7;
        }
    }
    float* er = ex[threadIdx.x];
    er[0]=b0; er[1]=b1; er[2]=b2; er[3]=b3; er[4]=b4; er[5]=b5; er[6]=b6; er[7]=b7;
    __syncthreads();
    if (threadIdx.x < 128) {
        int sh = qi >> 9;
        const float* A  = ex[threadIdx.x + (sh << 7)];
        const float* Bo = ex[threadIdx.x + ((1 - sh) << 7)];
        int* op = idx + (size_t)(base + qi) * 8;
        #pragma unroll
        for (int i = 0; i < 7; ++i) {
            float mm = fminf(A[i + 1], Bo[6 - i]);
            op[i] = base + (int)(__builtin_bit_cast(unsigned int, mm) & 1023u);
        }
        op[7] = base;   // pad (unused)
    }
}

// ---------------- 2: feat1 — x(16) -> packed qv1/ks1 uint[n][64] (lo=q/k, hi=v/s) ----------------
__global__ __launch_bounds__(256) void feat1_kernel(
    const float* __restrict__ x,
    const float* __restrict__ wk, const float* __restrict__ bk,
    const float* __restrict__ wq, const float* __restrict__ bq,
    const float* __restrict__ wv, const float* __restrict__ bv,
    const float* __restrict__ wsm, const float* __restrict__ bs,
    unsigned int* __restrict__ qv, unsigned int* __restrict__ ks) {
    int c = threadIdx.x & 63;
    float Wk[16], Wq[16], Wv[16], Ws[16];
    #pragma unroll
    for (int k = 0; k < 16; ++k) {
        Wk[k] = wk[k*64+c]; Wq[k] = wq[k*64+c]; Wv[k] = wv[k*64+c]; Ws[k] = wsm[k*64+c];
    }
    float Bk = bk[c], Bq = bq[c], Bv = bv[c], Bs = bs[c];
    int wave = blockIdx.x * (blockDim.x >> 6) + (threadIdx.x >> 6);
    int nw   = gridDim.x * (blockDim.x >> 6);
    for (int n = wave; n < NNODES; n += nw) {
        const float* xr = x + (size_t)n * 16;
        float ak = Bk, aq = Bq, av = Bv, as = Bs;
        #pragma unroll
        for (int k = 0; k < 16; ++k) {
            float xv = xr[k];
            ak += xv * Wk[k]; aq += xv * Wq[k]; av += xv * Wv[k]; as += xv * Ws[k];
        }
        size_t o = (size_t)n * 64 + c;
        qv[o] = ((unsigned int)f2bf(av) << 16) | f2bf(aq);
        ks[o] = ((unsigned int)f2bf(as) << 16) | f2bf(ak);
    }
}

// ---------------- 3: gated conv — scalar addressing, dwordx8 idx rows, unroll-4 -------------
template<int C>
__global__ __launch_bounds__(256) void conv_kernel(
    const unsigned int* __restrict__ qv, const unsigned int* __restrict__ ks,
    const int* __restrict__ idx, unsigned short* __restrict__ h,
    float* __restrict__ part) {
    const int NPB = 256 / C;
    int c   = threadIdx.x & (C - 1);
    int sub = __builtin_amdgcn_readfirstlane((int)(threadIdx.x / C));
    int b     = blockIdx.x;            // 4096 total = 128 graphs x 32
    int xcd   = b & 7;
    int chunk = b >> 3;
    int graph = xcd * 16 + (chunk >> 5);
    int nblk  = chunk & 31;
    int n0 = graph * NPER + nblk * 32;
    float s = 0.f, s2 = 0.f;
    #pragma unroll 4
    for (int i = sub; i < 32; i += NPB) {
        int n = n0 + i;                          // wave-uniform
        const int4* nb4 = (const int4*)(idx + (size_t)n * 8);
        int4 na = nb4[0];                        // s_load_dwordx4 (aligned 32B row)
        int4 nbv = nb4[1];
        unsigned int ku = ks[(size_t)n * C + c];
        float kv  = bf2f((unsigned short)(ku & 0xFFFF));
        float acc = bf2f((unsigned short)(ku >> 16));
        int jj[7] = {na.x, na.y, na.z, na.w, nbv.x, nbv.y, nbv.z};
        #pragma unroll
        for (int k = 0; k < NK; ++k) {
            int j = __builtin_amdgcn_readfirstlane(jj[k]);
            const unsigned int* p = qv + (size_t)j * C;
            unsigned int u = p[c];
            float qvv = bf2f((unsigned short)(u & 0xFFFF));
            float vvv = bf2f((unsigned short)(u >> 16));
            float t = kv + qvv;
            float sg = __builtin_amdgcn_rcpf(1.f + __expf(-t));
            acc = fmaf(sg, vvv, acc);
        }
        unsigned short hb = f2bf(acc);
        h[(size_t)n * C + c] = hb;
        float hv = bf2f(hb);
        s += hv; s2 += hv * hv;
    }
    __shared__ float ls[256], ls2[256];
    ls[threadIdx.x] = s; ls2[threadIdx.x] = s2;
    __syncthreads();
    if (threadIdx.x < C) {
        #pragma unroll
        for (int l = 1; l < NPB; ++l) { s += ls[threadIdx.x + l*C]; s2 += ls2[threadIdx.x + l*C]; }
        part[(size_t)blockIdx.x * 2 * C + threadIdx.x]     = s;
        part[(size_t)blockIdx.x * 2 * C + C + threadIdx.x] = s2;
    }
}

// ---------------- 4: BN finalize over 4096 block-partials ----------------
template<int C>
static __device__ __forceinline__ void bnfin_body(
    const float* __restrict__ part, const float* __restrict__ gamma,
    const float* __restrict__ beta, float* __restrict__ ss,
    int c, float* ls, float* ls2) {
    float s = 0.f, s2 = 0.f;
    for (int b = threadIdx.x; b < 4096; b += 256) {
        s  += part[(size_t)b * 2 * C + c];
        s2 += part[(size_t)b * 2 * C + C + c];
    }
    ls[threadIdx.x] = s; ls2[threadIdx.x] = s2;
    __syncthreads();
    for (int st = 128; st > 0; st >>= 1) {
        if (threadIdx.x < st) { ls[threadIdx.x] += ls[threadIdx.x+st]; ls2[threadIdx.x] += ls2[threadIdx.x+st]; }
        __syncthreads();
    }
    if (threadIdx.x == 0) {
        float m   = ls[0] / (float)NNODES;
        float var = ls2[0] / (float)NNODES - m * m;
        float inv = rsqrtf(var + 1e-5f);
        float sc  = gamma[c] * inv;
        ss[c]     = sc;
        ss[C + c] = beta[c] - m * sc;
    }
}

template<int C>
__global__ __launch_bounds__(256) void bnfin_kernel(
    const float* __restrict__ part, const float* __restrict__ gamma,
    const float* __restrict__ beta, float* __restrict__ ss) {
    __shared__ float ls[256], ls2[256];
    bnfin_body<C>(part, gamma, beta, ss, blockIdx.x, ls, ls2);
}

// ---------------- 5: merged BN1-finalize (blocks 0..63) + wfrag (blocks 64..127) ----------------
__global__ __launch_bounds__(256) void fin1_wfrag_kernel(
    const float* __restrict__ part, const float* __restrict__ gamma,
    const float* __restrict__ beta, float* __restrict__ ss,
    const float* __restrict__ w0, const float* __restrict__ w1,
    const float* __restrict__ w2, const float* __restrict__ w3,
    unsigned short* __restrict__ frag) {
    __shared__ float ls[256], ls2[256];
    if (blockIdx.x < 64) {
        bnfin_body<64>(part, gamma, beta, ss, blockIdx.x, ls, ls2);
        return;
    }
    int s  = blockIdx.x - 64;
    if (threadIdx.x >= 64) return;
    int m  = s >> 4;
    int kt = (s >> 3) & 1;
    int ct = s & 7;
    const float* w = (m == 0) ? w0 : (m == 1) ? w1 : (m == 2) ? w2 : w3;
    int l = threadIdx.x;
    int col = ct * 16 + (l & 15);
    int kbase = kt * 32 + (l >> 4) * 8;
    unsigned short* out = frag + ((size_t)s * 64 + l) * 8;
    #pragma unroll
    for (int e = 0; e < 8; ++e) out[e] = f2bf(w[(size_t)(kbase + e) * 128 + col]);
}

// ---------------- 7: feat2 — BN1+ReLU fused load, MFMA, LDS-exchange dword stores -------------
__global__ __launch_bounds__(256) void feat2_kernel(
    const unsigned short* __restrict__ h1n, const unsigned short* __restrict__ frag,
    const float* __restrict__ ss1,
    const float* __restrict__ b0, const float* __restrict__ b1,
    const float* __restrict__ b2, const float* __restrict__ b3,
    unsigned int* __restrict__ qv2, unsigned int* __restrict__ ks2) {
    __shared__ unsigned short xh[2][2][16][17];
    int nt = blockIdx.x;
    int m  = threadIdx.x >> 6;
    int l  = threadIdx.x & 63;
    const float* bm = (m == 0) ? b0 : (m == 1) ? b1 : (m == 2) ? b2 : b3;
    int lr = l & 15;
    int gq = l >> 4;
    int n  = nt * 16 + lr;
    const unsigned short* ar = h1n + (size_t)n * 64 + gq * 8;
    short8 a0r = *(const short8*)ar;
    short8 a1r = *(const short8*)(ar + 32);
    short8 a0, a1;
    #pragma unroll
    for (int e = 0; e < 8; ++e) {
        int c0 = gq * 8 + e;
        float f0 = bf2f((unsigned short)a0r[e]) * ss1[c0] + ss1[64 + c0];
        a0[e] = (short)f2bf(fmaxf(f0, 0.f));
        int c1 = 32 + gq * 8 + e;
        float f1 = bf2f((unsigned short)a1r[e]) * ss1[c1] + ss1[64 + c1];
        a1[e] = (short)f2bf(fmaxf(f1, 0.f));
    }
    #pragma unroll
    for (int ct = 0; ct < 8; ++ct) {
        size_t fb0 = ((size_t)(m * 16 + ct)     * 64 + l) * 8;
        size_t fb1 = ((size_t)(m * 16 + 8 + ct) * 64 + l) * 8;
        short8 w0 = *(const short8*)(frag + fb0);
        short8 w1 = *(const short8*)(frag + fb1);
        float bv = bm[ct * 16 + lr];
        floatx4 acc = {bv, bv, bv, bv};
        acc = __builtin_amdgcn_mfma_f32_16x16x32_bf16(a0, w0, acc, 0, 0, 0);
        acc = __builtin_amdgcn_mfma_f32_16x16x32_bf16(a1, w1, acc, 0, 0, 0);
        if (m >= 2) {
            #pragma unroll
            for (int r = 0; r < 4; ++r)
                xh[ct & 1][m - 2][gq * 4 + r][lr] = f2bf(acc[r]);
        }
        __syncthreads();
        if (m < 2) {
            unsigned int* od = (m == 1) ? qv2 : ks2;
            int set = (m == 1) ? 0 : 1;
            #pragma unroll
            for (int r = 0; r < 4; ++r) {
                unsigned int lo = f2bf(acc[r]);
                unsigned int hi = xh[ct & 1][set][gq * 4 + r][lr];
                od[(size_t)(nt * 16 + gq * 4 + r) * 128 + ct * 16 + lr] = (hi << 16) | lo;
            }
        }
    }
}

// ---------------- 8: mean-pool with fused BN2+ReLU, two-stage (1024 partial blocks) ----------
__global__ __launch_bounds__(256) void pool_partial_kernel(const unsigned short* __restrict__ h2,
                                                           const float* __restrict__ ss2,
                                                           float* __restrict__ part) {
    int g = blockIdx.x >> 3;
    int q = blockIdx.x & 7;
    int c = threadIdx.x & 127;
    int isub = threadIdx.x >> 7;  // 0..1
    float sc = ss2[c], sh = ss2[128 + c];
    float acc = 0.f;
    const unsigned short* hp = h2 + ((size_t)g * NPER + q * 128) * 128;
    for (int i = isub; i < 128; i += 2)
        acc += fmaxf(bf2f(hp[(size_t)i * 128 + c]) * sc + sh, 0.f);
    __shared__ float red[256];
    red[threadIdx.x] = acc;
    __syncthreads();
    if (threadIdx.x < 128)
        part[(size_t)blockIdx.x * 128 + c] = acc + red[threadIdx.x + 128];
}

__global__ void pool_final_kernel(const float* __restrict__ part, float* __restrict__ out) {
    int g = blockIdx.x, c = threadIdx.x;
    float s = 0.f;
    #pragma unroll
    for (int q = 0; q < 8; ++q) s += part[(size_t)(g * 8 + q) * 128 + c];
    out[(size_t)g * 128 + c] = s * (1.f / 1024.f);
}

extern "C" void kernel_launch(void* const* d_in, const int* in_sizes, int n_in,
                              void* d_out, int out_size, void* d_ws, size_t ws_size,
                              hipStream_t stream) {
    const float* x   = (const float*)d_in[0];
    const float* pos = (const float*)d_in[1];
    const float* wk1 = (const float*)d_in[3];
    const float* bk1 = (const float*)d_in[4];
    const float* wq1 = (const float*)d_in[5];
    const float* bq1 = (const float*)d_in[6];
    const float* wv1 = (const float*)d_in[7];
    const float* bv1 = (const float*)d_in[8];
    const float* ws1 = (const float*)d_in[9];
    const float* bs1 = (const float*)d_in[10];
    const float* g1  = (const float*)d_in[11];
    const float* be1 = (const float*)d_in[12];
    const float* wk2 = (const float*)d_in[13];
    const float* bk2 = (const float*)d_in[14];
    const float* wq2 = (const float*)d_in[15];
    const float* bq2 = (const float*)d_in[16];
    const float* wv2 = (const float*)d_in[17];
    const float* bv2 = (const float*)d_in[18];
    const float* ws2 = (const float*)d_in[19];
    const float* bs2 = (const float*)d_in[20];
    const float* g2  = (const float*)d_in[21];
    const float* be2 = (const float*)d_in[22];
    float* out = (float*)d_out;

    const size_t SZ_QV1 = (size_t)NNODES * 64 * 4;   // 32 MiB
    const size_t SZ_QV2 = (size_t)NNODES * 128 * 4;  // 64 MiB

    char* ws = (char*)d_ws;
    size_t off = 0;
    auto alloc = [&](size_t b) { size_t o = off; off += (b + 255) & ~(size_t)255; return o; };

    int* idx              = (int*)(ws + alloc((size_t)NNODES * 8 * 4));   // stride-8 rows
    size_t o_region       = alloc(2 * SZ_QV2);
    unsigned int* qv1     = (unsigned int*)(ws + o_region);
    unsigned int* ks1     = (unsigned int*)(ws + o_region + SZ_QV1);
    unsigned int* qv2     = (unsigned int*)(ws + o_region);
    unsigned int* ks2     = (unsigned int*)(ws + o_region + SZ_QV2);
    unsigned short* h1    = (unsigned short*)(ws + alloc((size_t)NNODES * 64 * 2));
    unsigned short* h2    = (unsigned short*)(ws + alloc((size_t)NNODES * 128 * 2));
    unsigned short* frag  = (unsigned short*)(ws + alloc(64 * 64 * 8 * 2));
    float* part           = (float*)(ws + alloc((size_t)4096 * 2 * 128 * 4));
    float* ss1            = (float*)(ws + alloc(2 * 64 * 4));
    float* ss2            = (float*)(ws + alloc(2 * 128 * 4));
    (void)ws_size; (void)in_sizes; (void)n_in; (void)out_size;

    knn_kernel<<<BGR * 8, 256, 0, stream>>>(pos, idx);
    feat1_kernel<<<1024, 256, 0, stream>>>(x, wk1, bk1, wq1, bq1, wv1, bv1, ws1, bs1,
                                           qv1, ks1);
    conv_kernel<64><<<NNODES / 32, 256, 0, stream>>>(qv1, ks1, idx, h1, part);
    fin1_wfrag_kernel<<<128, 256, 0, stream>>>(part, g1, be1, ss1,
                                               wk2, wq2, wv2, ws2, frag);
    feat2_kernel<<<NNODES / 16, 256, 0, stream>>>(h1, frag, ss1, bk2, bq2, bv2, bs2,
                                                  qv2, ks2);
    conv_kernel<128><<<NNODES / 32, 256, 0, stream>>>(qv2, ks2, idx, h2, part);
    bnfin_kernel<128><<<128, 256, 0, stream>>>(part, g2, be2, ss2);
    pool_partial_kernel<<<BGR * 8, 256, 0, stream>>>(h2, ss2, part);
    pool_final_kernel<<<BGR, 128, 0, stream>>>(part, out);
}